// Round 1
// baseline (539.984 us; speedup 1.0000x reference)
//
#include <hip/hip_runtime.h>
#include <hip/hip_bf16.h>

#define BB 2
#define SS 2048
#define EE 1024
#define HH 16
#define HD 64

typedef __attribute__((ext_vector_type(8))) __bf16 bf16x8;
typedef __attribute__((ext_vector_type(4))) __bf16 bf16x4;
typedef __attribute__((ext_vector_type(4))) float f32x4;

__device__ __forceinline__ void split2(float x, __bf16& h, __bf16& l) {
    h = (__bf16)x;                 // RTNE
    l = (__bf16)(x - (float)h);    // residual
}

// ---------------- K0: elementwise fp32 -> bf16 hi/lo split ----------------
__global__ __launch_bounds__(256) void k_split(const float* __restrict__ in,
                                               __bf16* __restrict__ hi,
                                               __bf16* __restrict__ lo, int n4)
{
    int i = blockIdx.x * 256 + threadIdx.x;
    if (i >= n4) return;
    const float4 v = *(const float4*)(in + (size_t)i * 4);
    float t[4] = {v.x, v.y, v.z, v.w};
    bf16x4 h4, l4;
#pragma unroll
    for (int e = 0; e < 4; ++e) {
        __bf16 h, l; split2(t[e], h, l);
        h4[e] = h; l4[e] = l;
    }
    *(bf16x4*)(hi + (size_t)i * 4) = h4;
    *(bf16x4*)(lo + (size_t)i * 4) = l4;
}

// ---------------- K1: QKV projection (split-bf16 GEMM, fp32-accurate) -----
// qkv[m][f] = sum_e x[m][e]*w[f][e] + b[f]; m=(b,s), f = h*192 + {q|k|v}*64 + d
// writes: q_ws fp32 [BH][S][HD]; kp_ws fp32 = k/8 + rel; vt_ws bf16 [BH][HD][S]
__global__ __launch_bounds__(256) void k_qkv(
    const __bf16* __restrict__ xhi, const __bf16* __restrict__ xlo,
    const __bf16* __restrict__ whi, const __bf16* __restrict__ wlo,
    const float* __restrict__ bqkv, const float* __restrict__ rel,
    float* __restrict__ q_ws, float* __restrict__ kp_ws,
    __bf16* __restrict__ vt_ws)
{
    __shared__ __bf16 Ahi[128][72], Alo[128][72];   // +8 pad: 2-way banks max
    __shared__ __bf16 Bhi[64][72],  Blo[64][72];

    const int tid = threadIdx.x;
    const int lane = tid & 63;
    const int wv = tid >> 6;
    const int m0 = blockIdx.y * 128;
    const int f0 = blockIdx.x * 64;
    const int wr = (wv >> 1) * 64, wc = (wv & 1) * 32;
    const int lr = lane & 15, lg = lane >> 4;

    f32x4 acc[4][2];
#pragma unroll
    for (int a = 0; a < 4; ++a)
#pragma unroll
        for (int b = 0; b < 2; ++b) acc[a][b] = (f32x4){0.f, 0.f, 0.f, 0.f};

    for (int kt = 0; kt < 16; ++kt) {
        const int k0 = kt * 64;
        __syncthreads();
        {   // stage A tile 128x64 (hi+lo)
            const int c = tid & 7, r0 = tid >> 3;
#pragma unroll
            for (int i = 0; i < 4; ++i) {
                const int row = r0 + i * 32;
                const size_t g = (size_t)(m0 + row) * EE + k0 + c * 8;
                *(bf16x8*)&Ahi[row][c * 8] = *(const bf16x8*)(xhi + g);
                *(bf16x8*)&Alo[row][c * 8] = *(const bf16x8*)(xlo + g);
            }
        }
        {   // stage B tile 64x64 (hi+lo)
            const int c = tid & 7, r0 = tid >> 3;
#pragma unroll
            for (int i = 0; i < 2; ++i) {
                const int row = r0 + i * 32;
                const size_t g = (size_t)(f0 + row) * EE + k0 + c * 8;
                *(bf16x8*)&Bhi[row][c * 8] = *(const bf16x8*)(whi + g);
                *(bf16x8*)&Blo[row][c * 8] = *(const bf16x8*)(wlo + g);
            }
        }
        __syncthreads();
#pragma unroll
        for (int ks = 0; ks < 2; ++ks) {
            const int koff = ks * 32 + lg * 8;
            bf16x8 ah[4], al[4], bh[2], bl[2];
#pragma unroll
            for (int rt = 0; rt < 4; ++rt) {
                ah[rt] = *(const bf16x8*)&Ahi[wr + rt * 16 + lr][koff];
                al[rt] = *(const bf16x8*)&Alo[wr + rt * 16 + lr][koff];
            }
#pragma unroll
            for (int ct = 0; ct < 2; ++ct) {
                bh[ct] = *(const bf16x8*)&Bhi[wc + ct * 16 + lr][koff];
                bl[ct] = *(const bf16x8*)&Blo[wc + ct * 16 + lr][koff];
            }
#pragma unroll
            for (int rt = 0; rt < 4; ++rt)
#pragma unroll
                for (int ct = 0; ct < 2; ++ct) {
                    acc[rt][ct] = __builtin_amdgcn_mfma_f32_16x16x32_bf16(ah[rt], bh[ct], acc[rt][ct], 0, 0, 0);
                    acc[rt][ct] = __builtin_amdgcn_mfma_f32_16x16x32_bf16(al[rt], bh[ct], acc[rt][ct], 0, 0, 0);
                    acc[rt][ct] = __builtin_amdgcn_mfma_f32_16x16x32_bf16(ah[rt], bl[ct], acc[rt][ct], 0, 0, 0);
                }
        }
    }

    // epilogue: tile's 64 f-cols are one (h, q/k/v) block since f0 % 64 == 0
    const int blk = f0 >> 6;             // 0..47
    const int h = blk / 3, typ = blk % 3;
#pragma unroll
    for (int rt = 0; rt < 4; ++rt) {
        const int m = m0 + wr + rt * 16 + lg * 4;
        const int b = m >> 11, s = m & 2047;
#pragma unroll
        for (int ct = 0; ct < 2; ++ct) {
            const int d = wc + ct * 16 + lr;
            const float bq = bqkv[f0 + d];
            if (typ == 0) {
                const size_t base = ((size_t)(b * HH + h) * SS + s) * HD + d;
#pragma unroll
                for (int r = 0; r < 4; ++r)
                    q_ws[base + (size_t)r * HD] = acc[rt][ct][r] + bq;
            } else if (typ == 1) {
                const size_t base = ((size_t)(b * HH + h) * SS + s) * HD + d;
                const size_t rb = ((size_t)h * SS + s) * HD + d;
#pragma unroll
                for (int r = 0; r < 4; ++r)
                    kp_ws[base + (size_t)r * HD] =
                        (acc[rt][ct][r] + bq) * 0.125f + rel[rb + (size_t)r * HD];
            } else {
                const size_t base = ((size_t)(b * HH + h) * HD + d) * SS + s;
                bf16x4 pk;
#pragma unroll
                for (int r = 0; r < 4; ++r) pk[r] = (__bf16)(acc[rt][ct][r] + bq);
                *(bf16x4*)&vt_ws[base] = pk;
            }
        }
    }
}

// ---------------- K2: fused attention -------------------------------------
// per block: 32 q-rows of one (b,h). logits = q·k' (split bf16, exact),
// u = exp(l) kept in LDS (bf16), PV accumulates unnormalized, Z reduced at
// end; weights = u/Z written once; av = PV/Z.
__global__ __launch_bounds__(512) void k_attn(
    const float* __restrict__ q_ws, const float* __restrict__ kp_ws,
    const __bf16* __restrict__ vt_ws,
    float* __restrict__ wts, __bf16* __restrict__ av_ws)
{
    __shared__ __bf16 U[32][2056];                    // 128.5 KB, pad 8
    __shared__ __bf16 KHI[64][72], KLO[64][72], VT[64][72];
    __shared__ float ZB[32];

    const int tid = threadIdx.x;
    const int lane = tid & 63;
    const int wv = tid >> 6;          // 8 waves
    const int rg = wv >> 2, cw = wv & 3;
    const int lr = lane & 15, lg = lane >> 4;

    const int ib = blockIdx.x & 63;
    const int bh = blockIdx.x >> 6;   // consecutive blocks share k'/v -> L2
    const int i0 = ib * 32;
    const size_t kvbase = (size_t)bh * SS * HD;

    if (tid < 32) ZB[tid] = 0.f;

    // preload this wave's q rows as split hi/lo A-fragments
    bf16x8 qhi[2], qlo[2];
    {
        const int row = i0 + rg * 16 + lr;
        const float* qp = q_ws + kvbase + (size_t)row * HD + lg * 8;
#pragma unroll
        for (int kk = 0; kk < 2; ++kk) {
            const float4 v0 = *(const float4*)(qp + kk * 32);
            const float4 v1 = *(const float4*)(qp + kk * 32 + 4);
            float t[8] = {v0.x, v0.y, v0.z, v0.w, v1.x, v1.y, v1.z, v1.w};
#pragma unroll
            for (int e = 0; e < 8; ++e) {
                __bf16 h, l; split2(t[e], h, l);
                qhi[kk][e] = h; qlo[kk][e] = l;
            }
        }
    }

    f32x4 accav = (f32x4){0.f, 0.f, 0.f, 0.f};
    float z4[4] = {0.f, 0.f, 0.f, 0.f};

    for (int jt = 0; jt < 32; ++jt) {
        const int j0 = jt * 64;
        __syncthreads();
        {   // stage k' (fp32 -> hi/lo bf16), 64x64
            const int row = tid >> 3, d0 = (tid & 7) * 8;
            const float* kp = kp_ws + kvbase + (size_t)(j0 + row) * HD + d0;
            const float4 v0 = *(const float4*)kp;
            const float4 v1 = *(const float4*)(kp + 4);
            float t[8] = {v0.x, v0.y, v0.z, v0.w, v1.x, v1.y, v1.z, v1.w};
            bf16x8 hi, lo;
#pragma unroll
            for (int e = 0; e < 8; ++e) {
                __bf16 h, l; split2(t[e], h, l);
                hi[e] = h; lo[e] = l;
            }
            *(bf16x8*)&KHI[row][d0] = hi;
            *(bf16x8*)&KLO[row][d0] = lo;
        }
        if (tid < 256) {   // stage v^T tile 64(d) x 64(j)
            const int dr = tid >> 2, joff = (tid & 3) * 16;
            const __bf16* vp = vt_ws + kvbase + (size_t)dr * SS + j0 + joff;
            *(bf16x8*)&VT[dr][joff]     = *(const bf16x8*)vp;
            *(bf16x8*)&VT[dr][joff + 8] = *(const bf16x8*)(vp + 8);
        }
        __syncthreads();

        // QK^T (3-term split: hi*hi + lo*hi + hi*lo)
        f32x4 acc = (f32x4){0.f, 0.f, 0.f, 0.f};
        {
            const int kr = cw * 16 + lr;
            const bf16x8 bh0 = *(const bf16x8*)&KHI[kr][lg * 8];
            const bf16x8 bh1 = *(const bf16x8*)&KHI[kr][32 + lg * 8];
            const bf16x8 bl0 = *(const bf16x8*)&KLO[kr][lg * 8];
            const bf16x8 bl1 = *(const bf16x8*)&KLO[kr][32 + lg * 8];
            acc = __builtin_amdgcn_mfma_f32_16x16x32_bf16(qhi[0], bh0, acc, 0, 0, 0);
            acc = __builtin_amdgcn_mfma_f32_16x16x32_bf16(qhi[1], bh1, acc, 0, 0, 0);
            acc = __builtin_amdgcn_mfma_f32_16x16x32_bf16(qlo[0], bh0, acc, 0, 0, 0);
            acc = __builtin_amdgcn_mfma_f32_16x16x32_bf16(qlo[1], bh1, acc, 0, 0, 0);
            acc = __builtin_amdgcn_mfma_f32_16x16x32_bf16(qhi[0], bl0, acc, 0, 0, 0);
            acc = __builtin_amdgcn_mfma_f32_16x16x32_bf16(qhi[1], bl1, acc, 0, 0, 0);
        }
        {   // u = exp(l); Z partial; stash u in LDS
            const int col = j0 + cw * 16 + lr;
            const int rbase = rg * 16 + lg * 4;
#pragma unroll
            for (int r = 0; r < 4; ++r) {
                const float u = __expf(acc[r]);
                z4[r] += u;
                U[rbase + r][col] = (__bf16)u;
            }
        }
        __syncthreads();
        {   // PV: av += u * v (unnormalized)
            const bf16x8 ua0 = *(const bf16x8*)&U[rg * 16 + lr][j0 + lg * 8];
            const bf16x8 ua1 = *(const bf16x8*)&U[rg * 16 + lr][j0 + 32 + lg * 8];
            const bf16x8 vb0 = *(const bf16x8*)&VT[cw * 16 + lr][lg * 8];
            const bf16x8 vb1 = *(const bf16x8*)&VT[cw * 16 + lr][32 + lg * 8];
            accav = __builtin_amdgcn_mfma_f32_16x16x32_bf16(ua0, vb0, accav, 0, 0, 0);
            accav = __builtin_amdgcn_mfma_f32_16x16x32_bf16(ua1, vb1, accav, 0, 0, 0);
        }
    }

    // Z: reduce across the 16 col-lanes of each lane-group, then across waves
#pragma unroll
    for (int m = 1; m < 16; m <<= 1) {
#pragma unroll
        for (int r = 0; r < 4; ++r) z4[r] += __shfl_xor(z4[r], m, 64);
    }
    if (lr == 0) {
        const int rbase = rg * 16 + lg * 4;
#pragma unroll
        for (int r = 0; r < 4; ++r) atomicAdd(&ZB[rbase + r], z4[r]);
    }
    __syncthreads();

    {   // av = PV/Z -> bf16 ws [B][S][E]
        const int b = bh >> 4, h = bh & 15;
        const int rbase = rg * 16 + lg * 4;
#pragma unroll
        for (int r = 0; r < 4; ++r) {
            const float av = accav[r] / ZB[rbase + r];
            const int s = i0 + rbase + r;
            av_ws[((size_t)(b * SS + s)) * EE + h * HD + cw * 16 + lr] = (__bf16)av;
        }
    }
    {   // weights = u/Z, coalesced fp32 writes
        const int r = tid >> 4;
        const int c0 = (tid & 15) * 4;
        const float rz = 1.0f / ZB[r];
        float* wp = wts + ((size_t)bh * SS + i0 + r) * SS;
#pragma unroll
        for (int it = 0; it < 32; ++it) {
            const int col = c0 + it * 64;
            const bf16x4 uu = *(const bf16x4*)&U[r][col];
            float4 o;
            o.x = (float)uu[0] * rz; o.y = (float)uu[1] * rz;
            o.z = (float)uu[2] * rz; o.w = (float)uu[3] * rz;
            *(float4*)(wp + col) = o;
        }
    }
}

// ---------------- K3: out projection (plain bf16) -------------------------
__global__ __launch_bounds__(256) void k_oproj(
    const __bf16* __restrict__ av_ws, const float* __restrict__ w_out,
    const float* __restrict__ b_out, float* __restrict__ out)
{
    __shared__ __bf16 Abf[128][72];
    __shared__ __bf16 Bbf[64][72];
    const int tid = threadIdx.x;
    const int lane = tid & 63;
    const int wv = tid >> 6;
    const int m0 = blockIdx.y * 128, f0 = blockIdx.x * 64;
    const int wr = (wv >> 1) * 64, wc = (wv & 1) * 32;
    const int lr = lane & 15, lg = lane >> 4;

    f32x4 acc[4][2];
#pragma unroll
    for (int a = 0; a < 4; ++a)
#pragma unroll
        for (int b = 0; b < 2; ++b) acc[a][b] = (f32x4){0.f, 0.f, 0.f, 0.f};

    for (int kt = 0; kt < 16; ++kt) {
        const int k0 = kt * 64;
        __syncthreads();
        {
            const int c = tid & 7, r0 = tid >> 3;
#pragma unroll
            for (int i = 0; i < 4; ++i) {
                const int row = r0 + i * 32;
                *(bf16x8*)&Abf[row][c * 8] =
                    *(const bf16x8*)(av_ws + (size_t)(m0 + row) * EE + k0 + c * 8);
            }
        }
        {
            const int c = tid & 15, r0 = tid >> 4;
#pragma unroll
            for (int i = 0; i < 4; ++i) {
                const int row = r0 + i * 16;
                const float4 v = *(const float4*)(w_out + (size_t)(f0 + row) * EE + k0 + c * 4);
                bf16x4 pk;
                pk[0] = (__bf16)v.x; pk[1] = (__bf16)v.y;
                pk[2] = (__bf16)v.z; pk[3] = (__bf16)v.w;
                *(bf16x4*)&Bbf[row][c * 4] = pk;
            }
        }
        __syncthreads();
#pragma unroll
        for (int ks = 0; ks < 2; ++ks) {
            const int koff = ks * 32 + lg * 8;
            bf16x8 a[4], b[2];
#pragma unroll
            for (int rt = 0; rt < 4; ++rt) a[rt] = *(const bf16x8*)&Abf[wr + rt * 16 + lr][koff];
#pragma unroll
            for (int ct = 0; ct < 2; ++ct) b[ct] = *(const bf16x8*)&Bbf[wc + ct * 16 + lr][koff];
#pragma unroll
            for (int rt = 0; rt < 4; ++rt)
#pragma unroll
                for (int ct = 0; ct < 2; ++ct)
                    acc[rt][ct] = __builtin_amdgcn_mfma_f32_16x16x32_bf16(a[rt], b[ct], acc[rt][ct], 0, 0, 0);
        }
    }
#pragma unroll
    for (int rt = 0; rt < 4; ++rt) {
        const int m = m0 + wr + rt * 16 + lg * 4;
#pragma unroll
        for (int ct = 0; ct < 2; ++ct) {
            const int f = f0 + wc + ct * 16 + lr;
            const float bo = b_out[f];
#pragma unroll
            for (int r = 0; r < 4; ++r)
                out[(size_t)(m + r) * EE + f] = acc[rt][ct][r] + bo;
        }
    }
}

extern "C" void kernel_launch(void* const* d_in, const int* in_sizes, int n_in,
                              void* d_out, int out_size, void* d_ws, size_t ws_size,
                              hipStream_t stream)
{
    const float* x    = (const float*)d_in[0];
    const float* wqkv = (const float*)d_in[1];
    const float* bqkv = (const float*)d_in[2];
    const float* wo   = (const float*)d_in[3];
    const float* bo   = (const float*)d_in[4];
    const float* rel  = (const float*)d_in[5];

    float* out = (float*)d_out;
    float* wts = out + (size_t)BB * SS * EE;      // weights region, written by K2

    const size_t NQ = (size_t)BB * HH * SS * HD;  // 4M elements
    float*  q_ws  = (float*)d_ws;                 // 16 MB
    float*  kp_ws = q_ws + NQ;                    // 16 MB
    __bf16* vt_ws = (__bf16*)(kp_ws + NQ);        //  8 MB
    __bf16* av_ws = vt_ws + NQ;                   //  8 MB  (ws total: 48 MB)

    // hi/lo splits of x and w_qkv live in the weights output region:
    // fully consumed by K1 before K2 overwrites it. (28 MB of 512 MB.)
    __bf16* xhi = (__bf16*)wts;
    __bf16* xlo = xhi + (size_t)BB * SS * EE;
    __bf16* whi = xlo + (size_t)BB * SS * EE;
    __bf16* wlo = whi + (size_t)3 * EE * EE;

    k_split<<<dim3((BB * SS * EE) / 1024), 256, 0, stream>>>(x, xhi, xlo, (BB * SS * EE) / 4);
    k_split<<<dim3((3 * EE * EE) / 1024), 256, 0, stream>>>(wqkv, whi, wlo, (3 * EE * EE) / 4);
    k_qkv<<<dim3(48, 32), 256, 0, stream>>>(xhi, xlo, whi, wlo, bqkv, rel, q_ws, kp_ws, vt_ws);
    k_attn<<<dim3(BB * HH * (SS / 32)), 512, 0, stream>>>(q_ws, kp_ws, vt_ws, wts, av_ws);
    k_oproj<<<dim3(EE / 64, (BB * SS) / 128), 256, 0, stream>>>(av_ws, wo, bo, out);
}